// Round 1
// baseline (270.744 us; speedup 1.0000x reference)
//
#include <hip/hip_runtime.h>

// One-pole IIR over time, B channels x T samples.
//   out_t = b0*x_t + s_t
//   s_{t+1} = b1*x_t + a1c*out_t = (b1 + a1c*b0)*x_t + a1c*s_t,  a1c = clamp(a1,-1,1)
// Chunked exact parallelization: per-chunk zero-init partial states (K1),
// per-channel chunk-level serial scan (K2), exact output pass (K3).

#define CHUNK 256  // time samples per thread-chunk (power of two)

__device__ __forceinline__ float clamp_a1(const float* a1p) {
    return fminf(fmaxf(a1p[0], -1.0f), 1.0f);
}

__global__ void k_partials(const float* __restrict__ x,
                           const float* __restrict__ b0p,
                           const float* __restrict__ b1p,
                           const float* __restrict__ a1p,
                           float* __restrict__ partial,  // [nch][B]
                           int B, int T, int nch) {
    int tid = blockIdx.x * blockDim.x + threadIdx.x;
    int total = B * nch;
    if (tid >= total) return;
    int b = tid / nch;
    int j = tid - b * nch;
    float a1c = clamp_a1(a1p);
    float c = b1p[0] + a1c * b0p[0];
    const float4* xp = (const float4*)(x + (size_t)b * T + (size_t)j * CHUNK);
    float s = 0.0f;
#pragma unroll 4
    for (int i = 0; i < CHUNK / 4; ++i) {
        float4 v = xp[i];
        s = fmaf(a1c, s, c * v.x);
        s = fmaf(a1c, s, c * v.y);
        s = fmaf(a1c, s, c * v.z);
        s = fmaf(a1c, s, c * v.w);
    }
    partial[(size_t)j * B + b] = s;
}

__global__ void k_scan(const float* __restrict__ partial,  // [nch][B]
                       const float* __restrict__ state,    // [B]
                       const float* __restrict__ a1p,
                       float* __restrict__ sstart,         // [nch][B]
                       float* __restrict__ final_state,    // [B]
                       int B, int nch) {
    int b = blockIdx.x * blockDim.x + threadIdx.x;
    if (b >= B) return;
    float a1c = clamp_a1(a1p);
    // d = a1c^CHUNK via repeated squaring (CHUNK is a power of two)
    float d = a1c;
    for (int e = 1; e < CHUNK; e <<= 1) d = d * d;
    float s = state[b];
    for (int j = 0; j < nch; ++j) {
        sstart[(size_t)j * B + b] = s;
        s = fmaf(d, s, partial[(size_t)j * B + b]);
    }
    final_state[b] = s;
}

__global__ void k_outputs(const float* __restrict__ x,
                          const float* __restrict__ b0p,
                          const float* __restrict__ b1p,
                          const float* __restrict__ a1p,
                          const float* __restrict__ sstart,  // [nch][B]
                          float* __restrict__ out,           // [B][T]
                          int B, int T, int nch) {
    int tid = blockIdx.x * blockDim.x + threadIdx.x;
    int total = B * nch;
    if (tid >= total) return;
    int b = tid / nch;
    int j = tid - b * nch;
    float a1c = clamp_a1(a1p);
    float b0 = b0p[0];
    float b1 = b1p[0];
    float s = sstart[(size_t)j * B + b];
    const float4* xp = (const float4*)(x + (size_t)b * T + (size_t)j * CHUNK);
    float4* op = (float4*)(out + (size_t)b * T + (size_t)j * CHUNK);
#pragma unroll 4
    for (int i = 0; i < CHUNK / 4; ++i) {
        float4 v = xp[i];
        float4 o;
        o.x = fmaf(b0, v.x, s); s = fmaf(b1, v.x, a1c * o.x);
        o.y = fmaf(b0, v.y, s); s = fmaf(b1, v.y, a1c * o.y);
        o.z = fmaf(b0, v.z, s); s = fmaf(b1, v.z, a1c * o.z);
        o.w = fmaf(b0, v.w, s); s = fmaf(b1, v.w, a1c * o.w);
        op[i] = o;
    }
}

extern "C" void kernel_launch(void* const* d_in, const int* in_sizes, int n_in,
                              void* d_out, int out_size, void* d_ws, size_t ws_size,
                              hipStream_t stream) {
    const float* x     = (const float*)d_in[0];
    const float* state = (const float*)d_in[1];
    const float* b0p   = (const float*)d_in[2];
    const float* b1p   = (const float*)d_in[3];
    const float* a1p   = (const float*)d_in[4];

    int B = in_sizes[1];                 // 4096
    int T = in_sizes[0] / B;             // 16384
    int nch = T / CHUNK;                 // 64 (T divisible by CHUNK for this problem)

    float* out         = (float*)d_out;                   // [B][T]
    float* final_state = (float*)d_out + (size_t)B * T;   // [B]

    // workspace: partial [nch][B] then sstart [nch][B]
    float* partial = (float*)d_ws;
    float* sstart  = partial + (size_t)nch * B;

    int total = B * nch;
    int block = 256;
    int grid1 = (total + block - 1) / block;

    k_partials<<<grid1, block, 0, stream>>>(x, b0p, b1p, a1p, partial, B, T, nch);
    k_scan<<<(B + block - 1) / block, block, 0, stream>>>(partial, state, a1p, sstart,
                                                          final_state, B, nch);
    k_outputs<<<grid1, block, 0, stream>>>(x, b0p, b1p, a1p, sstart, out, B, T, nch);
}

// Round 2
// 212.922 us; speedup vs baseline: 1.2716x; 1.2716x over previous
//
#include <hip/hip_runtime.h>

// One-pole IIR over time, B channels x T samples.
//   out_t = b0*x_t + s_t
//   s_{t+1} = b1*x_t + a1c*out_t = (b1 + a1c*b0)*x_t + a1c*s_t,  a1c = clamp(a1,-1,1)
//
// Fast path (decided at runtime): |a1c|^WARM < 1e-12 => each chunk's carry-in
// state is reconstructed from a WARM-sample warm-up window (zero-init), so a
// single fused kernel does one read of x and one write of out.
// Exact fallback path: 3-kernel chunked scan (partials -> chunk scan -> outputs),
// guarded by the mode flag (early-exit in fast mode).

#define CHUNK 256  // time samples per thread-chunk
#define WARM  64   // warm-up window (multiple of 4)

__device__ __forceinline__ float clamp_a1(const float* a1p) {
    return fminf(fmaxf(a1p[0], -1.0f), 1.0f);
}

__global__ void k_mode(const float* __restrict__ a1p, int* __restrict__ hdr) {
    float a1c = fminf(fmaxf(a1p[0], -1.0f), 1.0f);
    float decay = powf(fabsf(a1c), (float)WARM);
    hdr[0] = (decay < 1e-12f) ? 1 : 0;
}

__global__ void k_partials(const float* __restrict__ x,
                           const float* __restrict__ b0p,
                           const float* __restrict__ b1p,
                           const float* __restrict__ a1p,
                           const int* __restrict__ hdr,
                           float* __restrict__ partial,  // [nch][B]
                           int B, int T, int nch) {
    if (hdr[0]) return;  // fast mode: fused kernel handles everything
    int tid = blockIdx.x * blockDim.x + threadIdx.x;
    int total = B * nch;
    if (tid >= total) return;
    int b = tid / nch;
    int j = tid - b * nch;
    float a1c = clamp_a1(a1p);
    float c = fmaf(a1c, b0p[0], b1p[0]);
    const float4* xp = (const float4*)(x + (size_t)b * T + (size_t)j * CHUNK);
    float s = 0.0f;
#pragma unroll 8
    for (int i = 0; i < CHUNK / 4; ++i) {
        float4 v = xp[i];
        s = fmaf(a1c, s, c * v.x);
        s = fmaf(a1c, s, c * v.y);
        s = fmaf(a1c, s, c * v.z);
        s = fmaf(a1c, s, c * v.w);
    }
    partial[(size_t)j * B + b] = s;
}

__global__ void k_scan(const float* __restrict__ partial,  // [nch][B]
                       const float* __restrict__ state,    // [B]
                       const float* __restrict__ a1p,
                       const int* __restrict__ hdr,
                       float* __restrict__ sstart,         // [nch][B]
                       float* __restrict__ final_state,    // [B]
                       int B, int nch) {
    if (hdr[0]) return;
    int b = blockIdx.x * blockDim.x + threadIdx.x;
    if (b >= B) return;
    float a1c = clamp_a1(a1p);
    float d = a1c;
    for (int e = 1; e < CHUNK; e <<= 1) d = d * d;  // a1c^CHUNK
    float s = state[b];
    for (int j = 0; j < nch; ++j) {
        sstart[(size_t)j * B + b] = s;
        s = fmaf(d, s, partial[(size_t)j * B + b]);
    }
    final_state[b] = s;
}

__global__ void k_fused(const float* __restrict__ x,
                        const float* __restrict__ state,
                        const float* __restrict__ b0p,
                        const float* __restrict__ b1p,
                        const float* __restrict__ a1p,
                        const int* __restrict__ hdr,
                        const float* __restrict__ sstart,  // [nch][B] (exact mode)
                        float* __restrict__ out,           // [B][T]
                        float* __restrict__ final_state,   // [B]
                        int B, int T, int nch) {
    int tid = blockIdx.x * blockDim.x + threadIdx.x;
    int total = B * nch;
    if (tid >= total) return;
    int b = tid / nch;
    int j = tid - b * nch;
    float a1c = clamp_a1(a1p);
    float b0 = b0p[0];
    float b1 = b1p[0];
    int fast = hdr[0];

    const float* xb = x + (size_t)b * T + (size_t)j * CHUNK;
    float s;
    if (fast) {
        if (j == 0) {
            s = state[b];
        } else {
            // warm-up: reconstruct carry-in from the preceding WARM samples
            float c = fmaf(a1c, b0, b1);
            s = 0.0f;
            const float4* wp = (const float4*)(xb - WARM);
#pragma unroll
            for (int i = 0; i < WARM / 4; ++i) {
                float4 v = wp[i];
                s = fmaf(a1c, s, c * v.x);
                s = fmaf(a1c, s, c * v.y);
                s = fmaf(a1c, s, c * v.z);
                s = fmaf(a1c, s, c * v.w);
            }
        }
    } else {
        s = sstart[(size_t)j * B + b];
    }

    const float4* xp = (const float4*)xb;
    float4* op = (float4*)(out + (size_t)b * T + (size_t)j * CHUNK);
    // 32 samples per iteration: 8 batched loads -> compute -> 8 batched stores
    for (int blk = 0; blk < CHUNK / 32; ++blk) {
        float4 v[8], o[8];
#pragma unroll
        for (int u = 0; u < 8; ++u) v[u] = xp[blk * 8 + u];
#pragma unroll
        for (int u = 0; u < 8; ++u) {
            o[u].x = fmaf(b0, v[u].x, s); s = fmaf(b1, v[u].x, a1c * o[u].x);
            o[u].y = fmaf(b0, v[u].y, s); s = fmaf(b1, v[u].y, a1c * o[u].y);
            o[u].z = fmaf(b0, v[u].z, s); s = fmaf(b1, v[u].z, a1c * o[u].z);
            o[u].w = fmaf(b0, v[u].w, s); s = fmaf(b1, v[u].w, a1c * o[u].w);
        }
#pragma unroll
        for (int u = 0; u < 8; ++u) op[blk * 8 + u] = o[u];
    }

    if (fast && j == nch - 1) final_state[b] = s;
}

extern "C" void kernel_launch(void* const* d_in, const int* in_sizes, int n_in,
                              void* d_out, int out_size, void* d_ws, size_t ws_size,
                              hipStream_t stream) {
    const float* x     = (const float*)d_in[0];
    const float* state = (const float*)d_in[1];
    const float* b0p   = (const float*)d_in[2];
    const float* b1p   = (const float*)d_in[3];
    const float* a1p   = (const float*)d_in[4];

    int B = in_sizes[1];                 // 4096
    int T = in_sizes[0] / B;             // 16384
    int nch = T / CHUNK;                 // 64

    float* out         = (float*)d_out;                   // [B][T]
    float* final_state = (float*)d_out + (size_t)B * T;   // [B]

    // ws layout: [0..63] header ints; then partial [nch][B]; then sstart [nch][B]
    int*   hdr     = (int*)d_ws;
    float* partial = (float*)d_ws + 64;
    float* sstart  = partial + (size_t)nch * B;

    int total = B * nch;
    int block = 256;
    int grid1 = (total + block - 1) / block;

    k_mode<<<1, 1, 0, stream>>>(a1p, hdr);
    k_partials<<<grid1, block, 0, stream>>>(x, b0p, b1p, a1p, hdr, partial, B, T, nch);
    k_scan<<<(B + block - 1) / block, block, 0, stream>>>(partial, state, a1p, hdr,
                                                          sstart, final_state, B, nch);
    k_fused<<<grid1, block, 0, stream>>>(x, state, b0p, b1p, a1p, hdr, sstart,
                                         out, final_state, B, T, nch);
}

// Round 3
// 128.228 us; speedup vs baseline: 2.1114x; 1.6605x over previous
//
#include <hip/hip_runtime.h>

// One-pole IIR over time, B channels x T samples.
//   out_t = b0*x_t + s_t
//   s_{t+1} = b1*x_t + a1c*out_t = (b1 + a1c*b0)*x_t + a1c*s_t,  a1c = clamp(a1,-1,1)
//
// Fast path (runtime-selected): |a1c|^WARM < 1e-12 => each chunk's carry-in is
// reconstructed from a WARM-sample window, so one fused kernel does one read of
// x and one write of out, with wave-level coalescing through an LDS transpose:
//   wave = 64 channels x 256 timesteps; I/O in 64x32 subtiles where every
//   global load/store instruction covers 8 full 128B lines.
// Exact fallback path: 3-kernel chunked scan, guarded by the mode flag.

#define CHUNK 256  // time samples per wave-chunk
#define SUB   32   // subtile width (timesteps)
#define NSUB  (CHUNK / SUB)
#define WARM  32   // warm-up window = one subtile

__device__ __forceinline__ float clamp_a1(const float* a1p) {
    return fminf(fmaxf(a1p[0], -1.0f), 1.0f);
}

__global__ void k_mode(const float* __restrict__ a1p, int* __restrict__ hdr, int allow) {
    float a1c = fminf(fmaxf(a1p[0], -1.0f), 1.0f);
    float decay = powf(fabsf(a1c), (float)WARM);
    hdr[0] = (allow && decay < 1e-12f) ? 1 : 0;
}

// ---------------- exact fallback path ----------------

__global__ void k_partials(const float* __restrict__ x,
                           const float* __restrict__ b0p,
                           const float* __restrict__ b1p,
                           const float* __restrict__ a1p,
                           const int* __restrict__ hdr,
                           float* __restrict__ partial,  // [nch][B]
                           int B, int T, int nch) {
    if (hdr[0]) return;
    int tid = blockIdx.x * blockDim.x + threadIdx.x;
    int total = B * nch;
    if (tid >= total) return;
    int b = tid / nch;
    int j = tid - b * nch;
    float a1c = clamp_a1(a1p);
    float c = fmaf(a1c, b0p[0], b1p[0]);
    const float4* xp = (const float4*)(x + (size_t)b * T + (size_t)j * CHUNK);
    float s = 0.0f;
#pragma unroll 8
    for (int i = 0; i < CHUNK / 4; ++i) {
        float4 v = xp[i];
        s = fmaf(a1c, s, c * v.x);
        s = fmaf(a1c, s, c * v.y);
        s = fmaf(a1c, s, c * v.z);
        s = fmaf(a1c, s, c * v.w);
    }
    partial[(size_t)j * B + b] = s;
}

__global__ void k_scan(const float* __restrict__ partial,  // [nch][B]
                       const float* __restrict__ state,    // [B]
                       const float* __restrict__ a1p,
                       const int* __restrict__ hdr,
                       float* __restrict__ sstart,         // [nch][B]
                       float* __restrict__ final_state,    // [B]
                       int B, int nch) {
    if (hdr[0]) return;
    int b = blockIdx.x * blockDim.x + threadIdx.x;
    if (b >= B) return;
    float a1c = clamp_a1(a1p);
    float d = a1c;
    for (int e = 1; e < CHUNK; e <<= 1) d = d * d;  // a1c^CHUNK
    float s = state[b];
    for (int j = 0; j < nch; ++j) {
        sstart[(size_t)j * B + b] = s;
        s = fmaf(d, s, partial[(size_t)j * B + b]);
    }
    final_state[b] = s;
}

__global__ void k_exact_outputs(const float* __restrict__ x,
                                const float* __restrict__ b0p,
                                const float* __restrict__ b1p,
                                const float* __restrict__ a1p,
                                const int* __restrict__ hdr,
                                const float* __restrict__ sstart,  // [nch][B]
                                float* __restrict__ out,           // [B][T]
                                int B, int T, int nch) {
    if (hdr[0]) return;
    int tid = blockIdx.x * blockDim.x + threadIdx.x;
    int total = B * nch;
    if (tid >= total) return;
    int b = tid / nch;
    int j = tid - b * nch;
    float a1c = clamp_a1(a1p);
    float b0 = b0p[0];
    float b1 = b1p[0];
    float s = sstart[(size_t)j * B + b];
    const float4* xp = (const float4*)(x + (size_t)b * T + (size_t)j * CHUNK);
    float4* op = (float4*)(out + (size_t)b * T + (size_t)j * CHUNK);
#pragma unroll 4
    for (int i = 0; i < CHUNK / 4; ++i) {
        float4 v = xp[i];
        float4 o;
        o.x = fmaf(b0, v.x, s); s = fmaf(b1, v.x, a1c * o.x);
        o.y = fmaf(b0, v.y, s); s = fmaf(b1, v.y, a1c * o.y);
        o.z = fmaf(b0, v.z, s); s = fmaf(b1, v.z, a1c * o.z);
        o.w = fmaf(b0, v.w, s); s = fmaf(b1, v.w, a1c * o.w);
        op[i] = o;
    }
}

// ---------------- fast fused path (LDS-transposed coalesced I/O) ----------------

__global__ __launch_bounds__(256, 4)
void k_fused(const float* __restrict__ x,
             const float* __restrict__ state,
             const float* __restrict__ b0p,
             const float* __restrict__ b1p,
             const float* __restrict__ a1p,
             const int* __restrict__ hdr,
             float* __restrict__ out,           // [B][T]
             float* __restrict__ final_state,   // [B]
             int B, int T, int nch) {
    if (!hdr[0]) return;  // exact path active

    __shared__ float lds[4][64][SUB + 1];  // stride 33: (c+t)%32 bank rotation

    const int w    = threadIdx.x >> 6;
    const int lane = threadIdx.x & 63;
    const int nJgrp = nch >> 2;            // chunks handled 4-per-block (1/wave)
    const int bgrp = blockIdx.x / nJgrp;
    const int jgrp = blockIdx.x % nJgrp;
    const int j    = (jgrp << 2) + w;

    const float a1c = clamp_a1(a1p);
    const float b0  = b0p[0];
    const float b1  = b1p[0];

    // subtile load: 8 instrs, each = 8 full 128B lines (8 lanes per row segment)
    const int cl = (lane >> 3);         // row sub-index within group of 8
    const int t4 = (lane & 7) << 2;     // 16B slot within 32-float row

#define LOAD_SUBTILE(T0)                                                        \
    {                                                                           \
        _Pragma("unroll")                                                       \
        for (int r = 0; r < 8; ++r) {                                           \
            int c = (r << 3) + cl;                                              \
            float4 v = *(const float4*)(x + (size_t)(bgrp * 64 + c) * T + (T0) + t4); \
            lds[w][c][t4]     = v.x;                                            \
            lds[w][c][t4 + 1] = v.y;                                            \
            lds[w][c][t4 + 2] = v.z;                                            \
            lds[w][c][t4 + 3] = v.w;                                            \
        }                                                                       \
    }

    // ---- warm-up: reconstruct carry-in state for this chunk ----
    {
        int t0w = (j == 0) ? 0 : j * CHUNK - WARM;  // uniform control flow
        LOAD_SUBTILE(t0w);
        __syncthreads();
        float cwm = fmaf(a1c, b0, b1);
        float sw = 0.0f;
#pragma unroll
        for (int t = 0; t < SUB; ++t) {
            sw = fmaf(a1c, sw, cwm * lds[w][lane][t]);
        }
        __syncthreads();  // WAR: warm buffer reused by subtile 0
        if (j == 0) sw = state[bgrp * 64 + lane];
        float s = sw;

        // ---- main: 8 subtiles of 64ch x 32t ----
        for (int sub = 0; sub < NSUB; ++sub) {
            int t0 = j * CHUNK + sub * SUB;
            LOAD_SUBTILE(t0);
            __syncthreads();

            float v[SUB];
#pragma unroll
            for (int t = 0; t < SUB; ++t) v[t] = lds[w][lane][t];
#pragma unroll
            for (int t = 0; t < SUB; ++t) {
                float o = fmaf(b0, v[t], s);
                s = fmaf(b1, v[t], a1c * o);
                lds[w][lane][t] = o;
            }
            __syncthreads();

#pragma unroll
            for (int r = 0; r < 8; ++r) {
                int c = (r << 3) + cl;
                float4 ov;
                ov.x = lds[w][c][t4];
                ov.y = lds[w][c][t4 + 1];
                ov.z = lds[w][c][t4 + 2];
                ov.w = lds[w][c][t4 + 3];
                *(float4*)(out + (size_t)(bgrp * 64 + c) * T + t0 + t4) = ov;
            }
            __syncthreads();  // WAR before next subtile's load
        }

        if (j == nch - 1) final_state[bgrp * 64 + lane] = s;
    }
#undef LOAD_SUBTILE
}

extern "C" void kernel_launch(void* const* d_in, const int* in_sizes, int n_in,
                              void* d_out, int out_size, void* d_ws, size_t ws_size,
                              hipStream_t stream) {
    const float* x     = (const float*)d_in[0];
    const float* state = (const float*)d_in[1];
    const float* b0p   = (const float*)d_in[2];
    const float* b1p   = (const float*)d_in[3];
    const float* a1p   = (const float*)d_in[4];

    int B = in_sizes[1];                 // 4096
    int T = in_sizes[0] / B;             // 16384
    int nch = T / CHUNK;                 // 64

    float* out         = (float*)d_out;                   // [B][T]
    float* final_state = (float*)d_out + (size_t)B * T;   // [B]

    // ws layout: [0..63] header ints; then partial [nch][B]; then sstart [nch][B]
    int*   hdr     = (int*)d_ws;
    float* partial = (float*)d_ws + 64;
    float* sstart  = partial + (size_t)nch * B;

    int allow = (B % 64 == 0) && (T % CHUNK == 0) && (nch % 4 == 0) && (T == nch * CHUNK);

    int block = 256;
    int total = B * nch;
    int grid_exact = (total + block - 1) / block;

    k_mode<<<1, 1, 0, stream>>>(a1p, hdr, allow);

    // exact fallback (early-exits in fast mode)
    k_partials<<<grid_exact, block, 0, stream>>>(x, b0p, b1p, a1p, hdr, partial, B, T, nch);
    k_scan<<<(B + block - 1) / block, block, 0, stream>>>(partial, state, a1p, hdr,
                                                          sstart, final_state, B, nch);
    k_exact_outputs<<<grid_exact, block, 0, stream>>>(x, b0p, b1p, a1p, hdr, sstart,
                                                      out, B, T, nch);

    // fast fused path (early-exits in exact mode)
    if (allow) {
        int grid_fused = (B / 64) * (nch / 4);
        k_fused<<<grid_fused, block, 0, stream>>>(x, state, b0p, b1p, a1p, hdr,
                                                  out, final_state, B, T, nch);
    }
}